// Round 8
// baseline (460.457 us; speedup 1.0000x reference)
//
#include <hip/hip_runtime.h>
#include <hip/hip_bf16.h>
#include <cmath>

#define N_NODES 50000
#define N_EDGES 800000
#define N_GRAPHS 1024
#define F_IN 35
#define H1 10
#define C1 35
#define HC1 350
#define C2 128
#define NB256 196   // ceil(N_NODES/256)

typedef unsigned int uint32;
typedef __attribute__((ext_vector_type(8))) short short8;
typedef __attribute__((ext_vector_type(4))) float f32x4;
typedef __attribute__((ext_vector_type(4))) uint32 u32x4;

static __device__ __forceinline__ float bflo(uint32 u) { return __uint_as_float(u << 16); }
static __device__ __forceinline__ float bfhi(uint32 u) { return __uint_as_float(u & 0xffff0000u); }
static __device__ __forceinline__ unsigned short bfbits(float f) {
    return __builtin_bit_cast(unsigned short, __float2bfloat16(f));
}
static __device__ __forceinline__ uint32 packbf(float a, float b) {
    return ((uint32)bfbits(b) << 16) | (uint32)bfbits(a);
}
static __device__ __forceinline__ float lrelu(float e) { return (e > 0.f) ? e : 0.2f * e; }

// ---------------- CSR: count ----------------
__global__ void k_count(const int* __restrict__ dst, int* __restrict__ deg) {
    int e = blockIdx.x * blockDim.x + threadIdx.x;
    if (e < N_EDGES) atomicAdd(&deg[dst[e]], 1);
}

// ---------------- CSR: hierarchical scan ----------------
__global__ __launch_bounds__(256) void k_bsum(const int* __restrict__ deg, int* __restrict__ bsum) {
    const int i = blockIdx.x * 256 + threadIdx.x;
    int v = (i < N_NODES) ? deg[i] : 0;
#pragma unroll
    for (int off = 32; off; off >>= 1) v += __shfl_xor(v, off);
    __shared__ int ws[4];
    if ((threadIdx.x & 63) == 0) ws[threadIdx.x >> 6] = v;
    __syncthreads();
    if (threadIdx.x == 0) bsum[blockIdx.x] = ws[0] + ws[1] + ws[2] + ws[3];
}

__global__ __launch_bounds__(256) void k_bscan(const int* __restrict__ bsum, int* __restrict__ bpre) {
    __shared__ int buf[256];
    const int t = threadIdx.x;
    int v = (t < NB256) ? bsum[t] : 0;
    buf[t] = v;
    __syncthreads();
    for (int off = 1; off < 256; off <<= 1) {
        int u = (t >= off) ? buf[t - off] : 0;
        __syncthreads();
        buf[t] += u;
        __syncthreads();
    }
    if (t < NB256) bpre[t] = buf[t] - v;  // exclusive
}

__global__ __launch_bounds__(256) void k_boffs(const int* __restrict__ deg,
                                               const int* __restrict__ bpre,
                                               int* __restrict__ offs, int* __restrict__ cursor) {
    const int b = blockIdx.x, t = threadIdx.x;
    const int i = b * 256 + t;
    const int lane = t & 63, wid = t >> 6;
    int v = (i < N_NODES) ? deg[i] : 0;
    int s = v;
#pragma unroll
    for (int off = 1; off < 64; off <<= 1) {
        int u = __shfl_up(s, off);
        if (lane >= off) s += u;
    }
    __shared__ int wsum[4];
    if (lane == 63) wsum[wid] = s;
    __syncthreads();
    int wbase = 0;
    for (int w = 0; w < wid; ++w) wbase += wsum[w];
    int excl = bpre[b] + wbase + s - v;
    if (i < N_NODES) { offs[i] = excl; cursor[i] = excl; }
    if (i == 0) offs[N_NODES] = N_EDGES;
}

__global__ void k_fill(const int* __restrict__ src, const int* __restrict__ dst,
                       int* __restrict__ cursor, int* __restrict__ csr) {
    int e = blockIdx.x * blockDim.x + threadIdx.x;
    if (e < N_EDGES) {
        int p = atomicAdd(&cursor[dst[e]], 1);
        csr[p] = src[e];
    }
}

// ---------------- fused prep ----------------
#define XB ((N_NODES * 5 + 255) / 256)
__global__ __launch_bounds__(256) void k_prep(const float* __restrict__ x,
                                              const float* __restrict__ W1,
                                              const float* __restrict__ attS1,
                                              const float* __restrict__ attD1,
                                              const float* __restrict__ b1,
                                              const float* __restrict__ W2,
                                              uint32* __restrict__ xbf,
                                              float* __restrict__ fold,
                                              uint32* __restrict__ W1g,
                                              uint32* __restrict__ W2f) {
    const int b = blockIdx.x, t = threadIdx.x;
    if (b < XB) {
        int idx = b * 256 + t;
        if (idx >= N_NODES * 5) return;
        int n = idx / 5, s = idx - n * 5;
        uint32 o[4];
#pragma unroll
        for (int p = 0; p < 4; ++p) {
            int ch0 = s * 8 + 2 * p, ch1 = ch0 + 1;
            float a = (ch0 < F_IN) ? x[(size_t)n * F_IN + ch0] : (ch0 == 35 ? 1.f : 0.f);
            float bb = (ch1 < F_IN) ? x[(size_t)n * F_IN + ch1] : (ch1 == 35 ? 1.f : 0.f);
            o[p] = packbf(a, bb);
        }
        uint32* d = xbf + (size_t)idx * 4;
        d[0] = o[0]; d[1] = o[1]; d[2] = o[2]; d[3] = o[3];
    } else if (b < XB + 3) {
        int idx = (b - XB) * 256 + t;
        if (idx >= 700) return;
        int k = idx / 20, o = idx - k * 20;
        int h = (o < 10) ? o : o - 10;
        const float* att = (o < 10) ? attS1 : attD1;
        float s = 0.f;
        for (int c = 0; c < C1; ++c)
            s = fmaf(W1[k * HC1 + h * C1 + c], att[h * C1 + c], s);
        fold[k * 20 + o] = s;
    } else if (b < XB + 3 + 15) {
        int idx = (b - XB - 3) * 256 + t;
        if (idx >= 10 * 2 * 3 * 64) return;
        int lane = idx & 63;
        int rest = idx >> 6;
        int tt = rest % 3;
        int rest2 = rest / 3;
        int kk = rest2 & 1;
        int h = rest2 >> 1;
        int c = tt * 16 + (lane & 15);
        int k0 = kk * 32 + (lane >> 4) * 8;
        uint32 o[4];
#pragma unroll
        for (int jj = 0; jj < 4; ++jj) {
            float v[2];
#pragma unroll
            for (int half = 0; half < 2; ++half) {
                int k = k0 + 2 * jj + half;
                float val = 0.f;
                if (c < C1) {
                    if (k < F_IN) val = W1[k * HC1 + h * C1 + c];
                    else if (k == 35) val = b1[h * C1 + c];
                }
                v[half] = val;
            }
            o[jj] = packbf(v[0], v[1]);
        }
        uint32* d = W1g + (size_t)idx * 4;
        d[0] = o[0]; d[1] = o[1]; d[2] = o[2]; d[3] = o[3];
    } else {
        int idx = (b - XB - 3 - 15) * 256 + t;
        if (idx >= 11 * 8 * 64) return;
        int lane = idx & 63;
        int tt = (idx >> 6) & 7;
        int kk = idx >> 9;
        int c = tt * 16 + (lane & 15);
        int k0 = kk * 32 + (lane >> 4) * 8;
        uint32 o[4];
#pragma unroll
        for (int jj = 0; jj < 4; ++jj) {
            int ka = k0 + 2 * jj, kb = ka + 1;
            float va = (ka < HC1) ? W2[ka * C2 + c] : 0.f;
            float vb = (kb < HC1) ? W2[kb * C2 + c] : 0.f;
            o[jj] = packbf(va, vb);
        }
        uint32* d = W2f + (size_t)idx * 4;
        d[0] = o[0]; d[1] = o[1]; d[2] = o[2]; d[3] = o[3];
    }
}

// ---------------- attention pre-dots: a_s1/a_d1 = x @ fold (fp32) ----------------
__global__ __launch_bounds__(256) void k_att1(const float* __restrict__ x,
                                              const float* __restrict__ fold,
                                              float* __restrict__ a_s1,
                                              float* __restrict__ a_d1) {
    int idx = blockIdx.x * 256 + threadIdx.x;
    if (idx >= N_NODES * 20) return;
    int n = idx / 20, o = idx - n * 20;
    const float* xr = x + (size_t)n * F_IN;
    float acc = 0.f;
#pragma unroll
    for (int k = 0; k < F_IN; ++k) acc = fmaf(xr[k], fold[k * 20 + o], acc);
    if (o < 10) a_s1[n * 10 + o] = acc;
    else        a_d1[n * 10 + (o - 10)] = acc;
}

// ---------------- layer-1 aggregation in INPUT space ----------------
__global__ __launch_bounds__(256, 8) void k_aggx(const uint4* __restrict__ xbf4,  // [N][5]
                                                 const float* __restrict__ a_s,   // [N][10]
                                                 const float* __restrict__ a_d,   // [N][10]
                                                 const int* __restrict__ offs,
                                                 const int* __restrict__ csr,
                                                 uint32* __restrict__ aggx4) {    // [N*10][20]
    __shared__ float al[4][10][68];
    __shared__ float addl[4][10];
    __shared__ int totmax[4];
    const int tid = threadIdx.x, lane = tid & 63, wid = tid >> 6;
    const int d = blockIdx.x * 4 + wid;
    const int o0 = offs[d];
    const int deg = offs[d + 1] - o0;
    const int total = deg + 1;  // self-loop as edge 'deg'
    const int g = lane >> 4, u = lane & 15;
    const int hg = (u >= 10) ? 2 : ((u >= 5) ? 1 : 0);
    const int sl = u - hg * 5;
    const bool act = (u < 15);
    const int h0 = hg * 4;

    if (lane < 10) addl[wid][lane] = a_d[(size_t)d * 10 + lane];
    if (lane < 4) {
#pragma unroll
        for (int h = 0; h < 10; ++h) al[wid][h][64 + lane] = 0.f;  // jj-overrun pads
    }
    if (lane == 0) totmax[wid] = total;
    __syncthreads();
    const int tmx = max(max(totmax[0], totmax[1]), max(totmax[2], totmax[3]));
    const int rounds = (tmx + 63) >> 6;

    float acc[4][8];
#pragma unroll
    for (int a = 0; a < 4; ++a)
#pragma unroll
        for (int q = 0; q < 8; ++q) acc[a][q] = 0.f;

    for (int rb = 0; rb < rounds; ++rb) {
        const int base = rb << 6;
        const int i = base + lane;
        int s_mine = d;
        if (i < total) {
            if (i < deg) s_mine = __builtin_nontemporal_load(csr + o0 + i);
            const float2* ap = (const float2*)(a_s + (size_t)s_mine * 10);
            float2 p0 = ap[0], p1 = ap[1], p2 = ap[2], p3 = ap[3], p4 = ap[4];
            al[wid][0][lane] = __expf(lrelu(p0.x + addl[wid][0]));
            al[wid][1][lane] = __expf(lrelu(p0.y + addl[wid][1]));
            al[wid][2][lane] = __expf(lrelu(p1.x + addl[wid][2]));
            al[wid][3][lane] = __expf(lrelu(p1.y + addl[wid][3]));
            al[wid][4][lane] = __expf(lrelu(p2.x + addl[wid][4]));
            al[wid][5][lane] = __expf(lrelu(p2.y + addl[wid][5]));
            al[wid][6][lane] = __expf(lrelu(p3.x + addl[wid][6]));
            al[wid][7][lane] = __expf(lrelu(p3.y + addl[wid][7]));
            al[wid][8][lane] = __expf(lrelu(p4.x + addl[wid][8]));
            al[wid][9][lane] = __expf(lrelu(p4.y + addl[wid][9]));
        } else {
#pragma unroll
            for (int h = 0; h < 10; ++h) al[wid][h][lane] = 0.f;
        }
        __syncthreads();
        const int cnt = min(64, total - base);
        if (cnt > 0) {
            // prefetch depth 2 (4 edges per step)
            uint4 v0 = {0, 0, 0, 0}, v1 = {0, 0, 0, 0};
            {
                int s0 = __shfl(s_mine, g);
                if (act) v0 = xbf4[(size_t)s0 * 5 + sl];
            }
            if (4 < cnt) {
                int s1 = __shfl(s_mine, 4 + g);
                if (act) v1 = xbf4[(size_t)s1 * 5 + sl];
            }
            for (int jb = 0; jb < cnt; jb += 4) {
                uint4 w = v0;
                v0 = v1;
                const int jj = jb + g;  // al[.][.][jj]==0 for jj>=cnt (incl. pads 64..67)
                if (jb + 8 < cnt) {
                    int sn = __shfl(s_mine, jb + 8 + g);
                    if (act) v1 = xbf4[(size_t)sn * 5 + sl];
                }
                float f0 = bflo(w.x), f1 = bfhi(w.x), f2 = bflo(w.y), f3 = bfhi(w.y);
                float f4 = bflo(w.z), f5 = bfhi(w.z), f6 = bflo(w.w), f7 = bfhi(w.w);
#pragma unroll
                for (int a = 0; a < 4; ++a) {
                    const int hidx = min(h0 + a, 9);  // hg2 a>=2 dead (clamped, not stored)
                    const float aj = al[wid][hidx][jj];
                    acc[a][0] = fmaf(aj, f0, acc[a][0]);
                    acc[a][1] = fmaf(aj, f1, acc[a][1]);
                    acc[a][2] = fmaf(aj, f2, acc[a][2]);
                    acc[a][3] = fmaf(aj, f3, acc[a][3]);
                    acc[a][4] = fmaf(aj, f4, acc[a][4]);
                    acc[a][5] = fmaf(aj, f5, acc[a][5]);
                    acc[a][6] = fmaf(aj, f6, acc[a][6]);
                    acc[a][7] = fmaf(aj, f7, acc[a][7]);
                }
            }
        }
        __syncthreads();
    }
    // combine the 4 edge-groups
#pragma unroll
    for (int a = 0; a < 4; ++a)
#pragma unroll
        for (int q = 0; q < 8; ++q) {
            acc[a][q] += __shfl_xor(acc[a][q], 16);
            acc[a][q] += __shfl_xor(acc[a][q], 32);
        }
    const int nh = (hg == 2) ? 2 : 4;
#pragma unroll
    for (int a = 0; a < 4; ++a) {
        float den = __shfl(acc[a][3], hg * 5 + 4);  // ch35 (pseudo-one) = denominator
        float rdn = 1.f / den;
        if (g == 0 && act && a < nh) {
            u32x4 ov;
#pragma unroll
            for (int q = 0; q < 4; ++q)
                ov[q] = packbf(acc[a][2 * q] * rdn, acc[a][2 * q + 1] * rdn);
            // nt store: keep the 4MB xbf gather table L2-resident
            __builtin_nontemporal_store(ov,
                (u32x4*)&aggx4[(((size_t)d * 10 + h0 + a) * 5 + sl) * 4]);
        }
    }
}

// ---------------- layer-1 projection: x2p = elu( aggx @ W1g ) ----------------
__global__ __launch_bounds__(256, 8) void k_gemm1b(const short* __restrict__ aggx,  // [N*10][40]
                                                   const short8* __restrict__ W1g,
                                                   unsigned short* __restrict__ x2p) {  // [N][352]
    const int lane = threadIdx.x & 63;
    const int wid = threadIdx.x >> 6;
    const int mtile = blockIdx.x * 4 + wid;
    if (mtile >= N_NODES / 16) return;
    const int c_lo = lane & 15, grp = lane >> 4;
    const int m0 = mtile * 16;
    const size_t abase = (size_t)(m0 + c_lo) * 400 + grp * 8;

#pragma unroll
    for (int h = 0; h < 10; ++h) {
        const short* ap = aggx + abase + h * 40;
        short8 a0 = __builtin_nontemporal_load(reinterpret_cast<const short8*>(ap));
        short8 a1 = __builtin_nontemporal_load(reinterpret_cast<const short8*>(ap + 32));
        f32x4 acc[3];
#pragma unroll
        for (int tt = 0; tt < 3; ++tt) acc[tt] = (f32x4){0.f, 0.f, 0.f, 0.f};
#pragma unroll
        for (int tt = 0; tt < 3; ++tt)
            acc[tt] = __builtin_amdgcn_mfma_f32_16x16x32_bf16(a0, W1g[((h * 2 + 0) * 3 + tt) * 64 + lane], acc[tt], 0, 0, 0);
#pragma unroll
        for (int tt = 0; tt < 3; ++tt)
            acc[tt] = __builtin_amdgcn_mfma_f32_16x16x32_bf16(a1, W1g[((h * 2 + 1) * 3 + tt) * 64 + lane], acc[tt], 0, 0, 0);
#pragma unroll
        for (int tt = 0; tt < 3; ++tt) {
            int c = tt * 16 + c_lo;
            if (c < C1) {
#pragma unroll
                for (int r = 0; r < 4; ++r) {
                    int node = m0 + grp * 4 + r;
                    float v = acc[tt][r];
                    v = (v > 0.f) ? v : expm1f(v);
                    __builtin_nontemporal_store(bfbits(v), &x2p[(size_t)node * 352 + h * C1 + c]);
                }
            }
        }
    }
    if (lane < 16)
        __builtin_nontemporal_store(0u, &((uint32*)x2p)[(size_t)(m0 + lane) * 176 + 175]);
}

// ---------------- layer 2 GEMM via MFMA, fused att dots ----------------
__global__ __launch_bounds__(256) void k_gemm2(const short* __restrict__ x2p,       // [N][352]
                                               const short8* __restrict__ W2f,
                                               const float* __restrict__ attS,
                                               const float* __restrict__ attD,
                                               unsigned short* __restrict__ h2b,    // [N][128]
                                               float* __restrict__ a_s2, float* __restrict__ a_d2) {
    const int lane = threadIdx.x & 63;
    const int wid = threadIdx.x >> 6;
    const int mtile = blockIdx.x * 4 + wid;
    if (mtile >= N_NODES / 16) return;
    const int c_lo = lane & 15, grp = lane >> 4;
    const int m0 = mtile * 16;
    const short* aptr = x2p + (size_t)(m0 + c_lo) * 352 + grp * 8;

    f32x4 acc[8];
#pragma unroll
    for (int t = 0; t < 8; ++t) acc[t] = (f32x4){0.f, 0.f, 0.f, 0.f};
#pragma unroll
    for (int kk = 0; kk < 11; ++kk) {
        short8 a = __builtin_nontemporal_load(reinterpret_cast<const short8*>(aptr + kk * 32));
#pragma unroll
        for (int t = 0; t < 8; ++t) {
            short8 b = W2f[(kk * 8 + t) * 64 + lane];
            acc[t] = __builtin_amdgcn_mfma_f32_16x16x32_bf16(a, b, acc[t], 0, 0, 0);
        }
    }
    float attSv[8], attDv[8];
#pragma unroll
    for (int t = 0; t < 8; ++t) {
        attSv[t] = attS[t * 16 + c_lo];
        attDv[t] = attD[t * 16 + c_lo];
    }
    float ps[4] = {0, 0, 0, 0}, pd[4] = {0, 0, 0, 0};
#pragma unroll
    for (int t = 0; t < 8; ++t)
#pragma unroll
        for (int r = 0; r < 4; ++r) {
            ps[r] = fmaf(acc[t][r], attSv[t], ps[r]);
            pd[r] = fmaf(acc[t][r], attDv[t], pd[r]);
        }
#pragma unroll
    for (int r = 0; r < 4; ++r) {
        int node = m0 + grp * 4 + r;
#pragma unroll
        for (int t = 0; t < 8; ++t) h2b[(size_t)node * C2 + t * 16 + c_lo] = bfbits(acc[t][r]);
    }
#pragma unroll
    for (int r = 0; r < 4; ++r) {
        float s = ps[r], dd = pd[r];
#pragma unroll
        for (int off = 1; off < 16; off <<= 1) {
            s += __shfl_xor(s, off);
            dd += __shfl_xor(dd, off);
        }
        if (c_lo == 0) {
            int node = m0 + grp * 4 + r;
            a_s2[node] = s;
            a_d2[node] = dd;
        }
    }
}

// ---------------- layer-2 aggregation -> out2 fp32 (bias+relu) ----------------
__global__ __launch_bounds__(256, 8) void k_agg2(const uint4* __restrict__ feat4,  // h2b [N][16]
                                                 const float* __restrict__ a_s,   // [N]
                                                 const float* __restrict__ a_d,
                                                 const int* __restrict__ offs,
                                                 const int* __restrict__ csr,
                                                 const float* __restrict__ b2,    // [128]
                                                 float* __restrict__ out2) {      // [N][128]
    const int lane = threadIdx.x & 63;
    const int wid = threadIdx.x >> 6;
    const int d = blockIdx.x * 4 + wid;
    const int o0 = offs[d];
    const int deg = offs[d + 1] - o0;
    const int total = deg + 1;
    const float add = a_d[d];
    const int g = lane >> 4, cl = lane & 15;

    float acc[8];
#pragma unroll
    for (int q = 0; q < 8; ++q) acc[q] = 0.f;
    float den = 0.f;

    for (int base = 0; base < total; base += 64) {
        const int i = base + lane;
        int s_mine = d;
        float e_mine = 0.f;
        if (i < total) {
            if (i < deg) s_mine = __builtin_nontemporal_load(csr + o0 + i);
            e_mine = __expf(lrelu(a_s[s_mine] + add));
            den += e_mine;
        }
        const int cnt = min(64, total - base);
        // prefetch depth 2 (4 edges per step)
        float aj0 = __shfl(e_mine, g);
        uint4 v0 = feat4[(size_t)__shfl(s_mine, g) * 16 + cl];
        float aj1 = 0.f;
        uint4 v1 = {0, 0, 0, 0};
        if (4 < cnt) {
            aj1 = __shfl(e_mine, 4 + g);
            v1 = feat4[(size_t)__shfl(s_mine, 4 + g) * 16 + cl];
        }
        for (int jb = 0; jb < cnt; jb += 4) {
            uint4 v = v0;
            float a = aj0;
            v0 = v1; aj0 = aj1;
            if (jb + 8 < cnt) {
                int ni = jb + 8 + g;
                aj1 = __shfl(e_mine, ni);
                v1 = feat4[(size_t)__shfl(s_mine, ni) * 16 + cl];
            }
            acc[0] = fmaf(a, bflo(v.x), acc[0]);
            acc[1] = fmaf(a, bfhi(v.x), acc[1]);
            acc[2] = fmaf(a, bflo(v.y), acc[2]);
            acc[3] = fmaf(a, bfhi(v.y), acc[3]);
            acc[4] = fmaf(a, bflo(v.z), acc[4]);
            acc[5] = fmaf(a, bfhi(v.z), acc[5]);
            acc[6] = fmaf(a, bflo(v.w), acc[6]);
            acc[7] = fmaf(a, bfhi(v.w), acc[7]);
        }
    }
#pragma unroll
    for (int q = 0; q < 8; ++q) {
        acc[q] += __shfl_xor(acc[q], 16);
        acc[q] += __shfl_xor(acc[q], 32);
    }
#pragma unroll
    for (int off = 32; off > 0; off >>= 1) den += __shfl_xor(den, off);

    if (lane < 16) {
        const float rden = 1.f / den;
        const float4* bp = (const float4*)(b2 + 8 * cl);
        float4 b0 = bp[0], b1 = bp[1];
        f32x4 o0v, o1v;
        o0v[0] = fmaxf(acc[0] * rden + b0.x, 0.f);
        o0v[1] = fmaxf(acc[1] * rden + b0.y, 0.f);
        o0v[2] = fmaxf(acc[2] * rden + b0.z, 0.f);
        o0v[3] = fmaxf(acc[3] * rden + b0.w, 0.f);
        o1v[0] = fmaxf(acc[4] * rden + b1.x, 0.f);
        o1v[1] = fmaxf(acc[5] * rden + b1.y, 0.f);
        o1v[2] = fmaxf(acc[6] * rden + b1.z, 0.f);
        o1v[3] = fmaxf(acc[7] * rden + b1.w, 0.f);
        f32x4* op = (f32x4*)(out2 + (size_t)d * C2 + 8 * cl);
        __builtin_nontemporal_store(o0v, op);         // keep 12.8MB h2b table cached instead
        __builtin_nontemporal_store(o1v, op + 1);
    }
}

// ---------------- pooling: sorted-batch run-length max ----------------
__global__ __launch_bounds__(128) void k_pool(const float* __restrict__ out2,
                                              const int* __restrict__ batch,
                                              float* __restrict__ pooled) {
    const int c = threadIdx.x;
    const int n0 = blockIdx.x * 50;
    const int n1 = min(n0 + 50, N_NODES);
    int curB = batch[n0];
    float curM = 0.f;
    float v = __builtin_nontemporal_load(out2 + (size_t)n0 * C2 + c);
    for (int n = n0; n < n1; ++n) {
        float cur = v;
        int b = batch[n];
        if (n + 1 < n1) v = __builtin_nontemporal_load(out2 + (size_t)(n + 1) * C2 + c);
        if (b != curB) {
            atomicMax((int*)&pooled[curB * C2 + c], __float_as_int(curM));
            curB = b;
            curM = cur;
        } else {
            curM = fmaxf(curM, cur);
        }
    }
    atomicMax((int*)&pooled[curB * C2 + c], __float_as_int(curM));
}

// ---------------- dense head ----------------
__global__ __launch_bounds__(128) void k_head(const float* __restrict__ pooled,
                                              const float* __restrict__ Wg,
                                              const float* __restrict__ bg,
                                              const float* __restrict__ Wo,
                                              const float* __restrict__ bo,
                                              float* __restrict__ out) {
    __shared__ float p[C2];
    __shared__ float wsum[2];
    const int g = blockIdx.x;
    const int tid = threadIdx.x;
    p[tid] = pooled[g * C2 + tid];
    __syncthreads();
    float acc = bg[tid];
#pragma unroll 8
    for (int k = 0; k < C2; ++k) acc = fmaf(p[k], Wg[k * C2 + tid], acc);
    float z = fmaxf(acc, 0.f);
    float prod = z * Wo[tid];
#pragma unroll
    for (int off = 32; off; off >>= 1) prod += __shfl_down(prod, off);
    if ((tid & 63) == 0) wsum[tid >> 6] = prod;
    __syncthreads();
    if (tid == 0) out[g] = wsum[0] + wsum[1] + bo[0];
}

extern "C" void kernel_launch(void* const* d_in, const int* in_sizes, int n_in,
                              void* d_out, int out_size, void* d_ws, size_t ws_size,
                              hipStream_t stream) {
    const float* x        = (const float*)d_in[0];
    const int*   ei       = (const int*)d_in[1];
    const int*   batch    = (const int*)d_in[2];
    const float* W1       = (const float*)d_in[3];
    const float* att_src1 = (const float*)d_in[4];
    const float* att_dst1 = (const float*)d_in[5];
    const float* b1       = (const float*)d_in[6];
    const float* W2       = (const float*)d_in[7];
    const float* att_src2 = (const float*)d_in[8];
    const float* att_dst2 = (const float*)d_in[9];
    const float* b2       = (const float*)d_in[10];
    const float* Wg       = (const float*)d_in[11];
    const float* bg       = (const float*)d_in[12];
    const float* Wo       = (const float*)d_in[13];
    const float* bo       = (const float*)d_in[14];
    const int* src = ei;
    const int* dst = ei + N_EDGES;

    char* ws = (char*)d_ws;
    size_t off = 0;
    auto alloc = [&](size_t bytes) -> char* {
        char* p = ws + off;
        off = (off + bytes + 255) & ~(size_t)255;
        return p;
    };
    int*    deg    = (int*)alloc((size_t)N_NODES * 4);
    int*    offs   = (int*)alloc((size_t)(N_NODES + 1) * 4);
    int*    cursor = (int*)alloc((size_t)N_NODES * 4);
    int*    csr    = (int*)alloc((size_t)N_EDGES * 4);
    int*    bsum   = (int*)alloc((size_t)NB256 * 4);
    int*    bpre   = (int*)alloc((size_t)NB256 * 4);
    float*  a_s1   = (float*)alloc((size_t)N_NODES * H1 * 4);
    float*  a_d1   = (float*)alloc((size_t)N_NODES * H1 * 4);
    float*  a_s2   = (float*)alloc((size_t)N_NODES * 4);
    float*  a_d2   = (float*)alloc((size_t)N_NODES * 4);
    float*  pooled = (float*)alloc((size_t)N_GRAPHS * C2 * 4);
    float*  fold   = (float*)alloc((size_t)700 * 4);
    uint32* xbf    = (uint32*)alloc((size_t)N_NODES * 20 * 4);        // [N][40] bf16
    uint32* aggx   = (uint32*)alloc((size_t)N_NODES * 200 * 4 + 256); // [N*10][40] bf16 + slack
    uint32* x2p    = (uint32*)alloc((size_t)N_NODES * 176 * 4);       // [N][352] bf16
    unsigned short* h2b = (unsigned short*)alloc((size_t)N_NODES * C2 * 2);
    uint32* W1g    = (uint32*)alloc((size_t)10 * 2 * 3 * 64 * 16);
    uint32* W2f    = (uint32*)alloc((size_t)11 * 8 * 64 * 16);
    float*  out2   = (float*)aggx;  // aggx dead after k_gemm1b; 25.6 MB fits in 40 MB

    hipMemsetAsync(deg, 0, (size_t)N_NODES * 4, stream);
    hipMemsetAsync(pooled, 0, (size_t)N_GRAPHS * C2 * 4, stream);

    k_count<<<(N_EDGES + 255) / 256, 256, 0, stream>>>(dst, deg);
    k_bsum<<<NB256, 256, 0, stream>>>(deg, bsum);
    k_bscan<<<1, 256, 0, stream>>>(bsum, bpre);
    k_boffs<<<NB256, 256, 0, stream>>>(deg, bpre, offs, cursor);
    k_fill<<<(N_EDGES + 255) / 256, 256, 0, stream>>>(src, dst, cursor, csr);

    k_prep<<<XB + 3 + 15 + 22, 256, 0, stream>>>(x, W1, att_src1, att_dst1, b1, W2,
                                                 xbf, fold, W1g, W2f);
    k_att1<<<(N_NODES * 20 + 255) / 256, 256, 0, stream>>>(x, fold, a_s1, a_d1);

    k_aggx<<<N_NODES / 4, 256, 0, stream>>>((const uint4*)xbf, a_s1, a_d1, offs, csr, aggx);

    k_gemm1b<<<(N_NODES / 16 + 3) / 4, 256, 0, stream>>>((const short*)aggx, (const short8*)W1g,
                                                         (unsigned short*)x2p);

    k_gemm2<<<(N_NODES / 16 + 3) / 4, 256, 0, stream>>>((const short*)x2p, (const short8*)W2f,
                                                        att_src2, att_dst2, h2b, a_s2, a_d2);

    k_agg2<<<N_NODES / 4, 256, 0, stream>>>((const uint4*)h2b, a_s2, a_d2, offs, csr, b2, out2);

    k_pool<<<(N_NODES + 49) / 50, 128, 0, stream>>>(out2, batch, pooled);

    k_head<<<N_GRAPHS, 128, 0, stream>>>(pooled, Wg, bg, Wo, bo, (float*)d_out);
}

// Round 9
// 409.620 us; speedup vs baseline: 1.1241x; 1.1241x over previous
//
#include <hip/hip_runtime.h>
#include <hip/hip_bf16.h>
#include <cmath>

#define N_NODES 50000
#define N_EDGES 800000
#define N_GRAPHS 1024
#define F_IN 35
#define H1 10
#define C1 35
#define HC1 350
#define C2 128
#define NB256 196   // ceil(N_NODES/256)

typedef unsigned int uint32;
typedef __attribute__((ext_vector_type(8))) short short8;
typedef __attribute__((ext_vector_type(4))) float f32x4;
typedef __attribute__((ext_vector_type(4))) uint32 u32x4;

static __device__ __forceinline__ float bflo(uint32 u) { return __uint_as_float(u << 16); }
static __device__ __forceinline__ float bfhi(uint32 u) { return __uint_as_float(u & 0xffff0000u); }
static __device__ __forceinline__ unsigned short bfbits(float f) {
    return __builtin_bit_cast(unsigned short, __float2bfloat16(f));
}
static __device__ __forceinline__ uint32 packbf(float a, float b) {
    return ((uint32)bfbits(b) << 16) | (uint32)bfbits(a);
}
static __device__ __forceinline__ float lrelu(float e) { return (e > 0.f) ? e : 0.2f * e; }

// ---------------- CSR: count ----------------
__global__ void k_count(const int* __restrict__ dst, int* __restrict__ deg) {
    int e = blockIdx.x * blockDim.x + threadIdx.x;
    if (e < N_EDGES) atomicAdd(&deg[dst[e]], 1);
}

// ---------------- CSR: hierarchical scan ----------------
__global__ __launch_bounds__(256) void k_bsum(const int* __restrict__ deg, int* __restrict__ bsum) {
    const int i = blockIdx.x * 256 + threadIdx.x;
    int v = (i < N_NODES) ? deg[i] : 0;
#pragma unroll
    for (int off = 32; off; off >>= 1) v += __shfl_xor(v, off);
    __shared__ int ws[4];
    if ((threadIdx.x & 63) == 0) ws[threadIdx.x >> 6] = v;
    __syncthreads();
    if (threadIdx.x == 0) bsum[blockIdx.x] = ws[0] + ws[1] + ws[2] + ws[3];
}

__global__ __launch_bounds__(256) void k_bscan(const int* __restrict__ bsum, int* __restrict__ bpre) {
    __shared__ int buf[256];
    const int t = threadIdx.x;
    int v = (t < NB256) ? bsum[t] : 0;
    buf[t] = v;
    __syncthreads();
    for (int off = 1; off < 256; off <<= 1) {
        int u = (t >= off) ? buf[t - off] : 0;
        __syncthreads();
        buf[t] += u;
        __syncthreads();
    }
    if (t < NB256) bpre[t] = buf[t] - v;  // exclusive
}

__global__ __launch_bounds__(256) void k_boffs(const int* __restrict__ deg,
                                               const int* __restrict__ bpre,
                                               int* __restrict__ offs, int* __restrict__ cursor) {
    const int b = blockIdx.x, t = threadIdx.x;
    const int i = b * 256 + t;
    const int lane = t & 63, wid = t >> 6;
    int v = (i < N_NODES) ? deg[i] : 0;
    int s = v;
#pragma unroll
    for (int off = 1; off < 64; off <<= 1) {
        int u = __shfl_up(s, off);
        if (lane >= off) s += u;
    }
    __shared__ int wsum[4];
    if (lane == 63) wsum[wid] = s;
    __syncthreads();
    int wbase = 0;
    for (int w = 0; w < wid; ++w) wbase += wsum[w];
    int excl = bpre[b] + wbase + s - v;
    if (i < N_NODES) { offs[i] = excl; cursor[i] = excl; }
    if (i == 0) offs[N_NODES] = N_EDGES;
}

__global__ void k_fill(const int* __restrict__ src, const int* __restrict__ dst,
                       int* __restrict__ cursor, int* __restrict__ csr) {
    int e = blockIdx.x * blockDim.x + threadIdx.x;
    if (e < N_EDGES) {
        int p = atomicAdd(&cursor[dst[e]], 1);
        csr[p] = src[e];
    }
}

// ---------------- fused prep ----------------
#define XB ((N_NODES * 5 + 255) / 256)
__global__ __launch_bounds__(256) void k_prep(const float* __restrict__ x,
                                              const float* __restrict__ W1,
                                              const float* __restrict__ attS1,
                                              const float* __restrict__ attD1,
                                              const float* __restrict__ b1,
                                              const float* __restrict__ W2,
                                              uint32* __restrict__ xbf,
                                              float* __restrict__ fold,
                                              uint32* __restrict__ W1g,
                                              uint32* __restrict__ W2f) {
    const int b = blockIdx.x, t = threadIdx.x;
    if (b < XB) {
        int idx = b * 256 + t;
        if (idx >= N_NODES * 5) return;
        int n = idx / 5, s = idx - n * 5;
        uint32 o[4];
#pragma unroll
        for (int p = 0; p < 4; ++p) {
            int ch0 = s * 8 + 2 * p, ch1 = ch0 + 1;
            float a = (ch0 < F_IN) ? x[(size_t)n * F_IN + ch0] : (ch0 == 35 ? 1.f : 0.f);
            float bb = (ch1 < F_IN) ? x[(size_t)n * F_IN + ch1] : (ch1 == 35 ? 1.f : 0.f);
            o[p] = packbf(a, bb);
        }
        uint32* d = xbf + (size_t)idx * 4;
        d[0] = o[0]; d[1] = o[1]; d[2] = o[2]; d[3] = o[3];
    } else if (b < XB + 3) {
        int idx = (b - XB) * 256 + t;
        if (idx >= 700) return;
        int k = idx / 20, o = idx - k * 20;
        int h = (o < 10) ? o : o - 10;
        const float* att = (o < 10) ? attS1 : attD1;
        float s = 0.f;
        for (int c = 0; c < C1; ++c)
            s = fmaf(W1[k * HC1 + h * C1 + c], att[h * C1 + c], s);
        fold[k * 20 + o] = s;
    } else if (b < XB + 3 + 15) {
        int idx = (b - XB - 3) * 256 + t;
        if (idx >= 10 * 2 * 3 * 64) return;
        int lane = idx & 63;
        int rest = idx >> 6;
        int tt = rest % 3;
        int rest2 = rest / 3;
        int kk = rest2 & 1;
        int h = rest2 >> 1;
        int c = tt * 16 + (lane & 15);
        int k0 = kk * 32 + (lane >> 4) * 8;
        uint32 o[4];
#pragma unroll
        for (int jj = 0; jj < 4; ++jj) {
            float v[2];
#pragma unroll
            for (int half = 0; half < 2; ++half) {
                int k = k0 + 2 * jj + half;
                float val = 0.f;
                if (c < C1) {
                    if (k < F_IN) val = W1[k * HC1 + h * C1 + c];
                    else if (k == 35) val = b1[h * C1 + c];
                }
                v[half] = val;
            }
            o[jj] = packbf(v[0], v[1]);
        }
        uint32* d = W1g + (size_t)idx * 4;
        d[0] = o[0]; d[1] = o[1]; d[2] = o[2]; d[3] = o[3];
    } else {
        int idx = (b - XB - 3 - 15) * 256 + t;
        if (idx >= 11 * 8 * 64) return;
        int lane = idx & 63;
        int tt = (idx >> 6) & 7;
        int kk = idx >> 9;
        int c = tt * 16 + (lane & 15);
        int k0 = kk * 32 + (lane >> 4) * 8;
        uint32 o[4];
#pragma unroll
        for (int jj = 0; jj < 4; ++jj) {
            int ka = k0 + 2 * jj, kb = ka + 1;
            float va = (ka < HC1) ? W2[ka * C2 + c] : 0.f;
            float vb = (kb < HC1) ? W2[kb * C2 + c] : 0.f;
            o[jj] = packbf(va, vb);
        }
        uint32* d = W2f + (size_t)idx * 4;
        d[0] = o[0]; d[1] = o[1]; d[2] = o[2]; d[3] = o[3];
    }
}

// ---------------- attention pre-dots: a_s1/a_d1 = x @ fold (fp32) ----------------
__global__ __launch_bounds__(256) void k_att1(const float* __restrict__ x,
                                              const float* __restrict__ fold,
                                              float* __restrict__ a_s1,
                                              float* __restrict__ a_d1) {
    int idx = blockIdx.x * 256 + threadIdx.x;
    if (idx >= N_NODES * 20) return;
    int n = idx / 20, o = idx - n * 20;
    const float* xr = x + (size_t)n * F_IN;
    float acc = 0.f;
#pragma unroll
    for (int k = 0; k < F_IN; ++k) acc = fmaf(xr[k], fold[k * 20 + o], acc);
    if (o < 10) a_s1[n * 10 + o] = acc;
    else        a_d1[n * 10 + (o - 10)] = acc;
}

// ---------------- layer-1 aggregation in INPUT space ----------------
// output rows padded to 832B/node (52 uint4, 64B multiple) for full-line NT stores
__global__ __launch_bounds__(256, 8) void k_aggx(const uint4* __restrict__ xbf4,  // [N][5]
                                                 const float* __restrict__ a_s,   // [N][10]
                                                 const float* __restrict__ a_d,   // [N][10]
                                                 const int* __restrict__ offs,
                                                 const int* __restrict__ csr,
                                                 uint32* __restrict__ aggx4) {    // [N][52 u4]
    __shared__ float al[4][10][68];
    __shared__ float addl[4][10];
    __shared__ int totmax[4];
    __shared__ uint4 stage[4][50];
    const int tid = threadIdx.x, lane = tid & 63, wid = tid >> 6;
    const int d = blockIdx.x * 4 + wid;
    const int o0 = offs[d];
    const int deg = offs[d + 1] - o0;
    const int total = deg + 1;  // self-loop as edge 'deg'
    const int g = lane >> 4, u = lane & 15;
    const int hg = (u >= 10) ? 2 : ((u >= 5) ? 1 : 0);
    const int sl = u - hg * 5;
    const bool act = (u < 15);
    const int h0 = hg * 4;

    if (lane < 10) addl[wid][lane] = a_d[(size_t)d * 10 + lane];
    if (lane < 4) {
#pragma unroll
        for (int h = 0; h < 10; ++h) al[wid][h][64 + lane] = 0.f;  // jj-overrun pads
    }
    if (lane == 0) totmax[wid] = total;
    __syncthreads();
    const int tmx = max(max(totmax[0], totmax[1]), max(totmax[2], totmax[3]));
    const int rounds = (tmx + 63) >> 6;

    float acc[4][8];
#pragma unroll
    for (int a = 0; a < 4; ++a)
#pragma unroll
        for (int q = 0; q < 8; ++q) acc[a][q] = 0.f;

    for (int rb = 0; rb < rounds; ++rb) {
        const int base = rb << 6;
        const int i = base + lane;
        int s_mine = d;
        if (i < total) {
            if (i < deg) s_mine = __builtin_nontemporal_load(csr + o0 + i);
            const float2* ap = (const float2*)(a_s + (size_t)s_mine * 10);
            float2 p0 = ap[0], p1 = ap[1], p2 = ap[2], p3 = ap[3], p4 = ap[4];
            al[wid][0][lane] = __expf(lrelu(p0.x + addl[wid][0]));
            al[wid][1][lane] = __expf(lrelu(p0.y + addl[wid][1]));
            al[wid][2][lane] = __expf(lrelu(p1.x + addl[wid][2]));
            al[wid][3][lane] = __expf(lrelu(p1.y + addl[wid][3]));
            al[wid][4][lane] = __expf(lrelu(p2.x + addl[wid][4]));
            al[wid][5][lane] = __expf(lrelu(p2.y + addl[wid][5]));
            al[wid][6][lane] = __expf(lrelu(p3.x + addl[wid][6]));
            al[wid][7][lane] = __expf(lrelu(p3.y + addl[wid][7]));
            al[wid][8][lane] = __expf(lrelu(p4.x + addl[wid][8]));
            al[wid][9][lane] = __expf(lrelu(p4.y + addl[wid][9]));
        } else {
#pragma unroll
            for (int h = 0; h < 10; ++h) al[wid][h][lane] = 0.f;
        }
        __syncthreads();
        const int cnt = min(64, total - base);
        if (cnt > 0) {
            // prefetch depth 2 (4 edges per step)
            uint4 v0 = {0, 0, 0, 0}, v1 = {0, 0, 0, 0};
            {
                int s0 = __shfl(s_mine, g);
                if (act) v0 = xbf4[(size_t)s0 * 5 + sl];
            }
            if (4 < cnt) {
                int s1 = __shfl(s_mine, 4 + g);
                if (act) v1 = xbf4[(size_t)s1 * 5 + sl];
            }
            for (int jb = 0; jb < cnt; jb += 4) {
                uint4 w = v0;
                v0 = v1;
                const int jj = jb + g;  // al[.][.][jj]==0 for jj>=cnt (incl. pads 64..67)
                if (jb + 8 < cnt) {
                    int sn = __shfl(s_mine, jb + 8 + g);
                    if (act) v1 = xbf4[(size_t)sn * 5 + sl];
                }
                float f0 = bflo(w.x), f1 = bfhi(w.x), f2 = bflo(w.y), f3 = bfhi(w.y);
                float f4 = bflo(w.z), f5 = bfhi(w.z), f6 = bflo(w.w), f7 = bfhi(w.w);
#pragma unroll
                for (int a = 0; a < 4; ++a) {
                    const int hidx = min(h0 + a, 9);  // hg2 a>=2 dead (clamped, not stored)
                    const float aj = al[wid][hidx][jj];
                    acc[a][0] = fmaf(aj, f0, acc[a][0]);
                    acc[a][1] = fmaf(aj, f1, acc[a][1]);
                    acc[a][2] = fmaf(aj, f2, acc[a][2]);
                    acc[a][3] = fmaf(aj, f3, acc[a][3]);
                    acc[a][4] = fmaf(aj, f4, acc[a][4]);
                    acc[a][5] = fmaf(aj, f5, acc[a][5]);
                    acc[a][6] = fmaf(aj, f6, acc[a][6]);
                    acc[a][7] = fmaf(aj, f7, acc[a][7]);
                }
            }
        }
        __syncthreads();
    }
    // combine the 4 edge-groups
#pragma unroll
    for (int a = 0; a < 4; ++a)
#pragma unroll
        for (int q = 0; q < 8; ++q) {
            acc[a][q] += __shfl_xor(acc[a][q], 16);
            acc[a][q] += __shfl_xor(acc[a][q], 32);
        }
    const int nh = (hg == 2) ? 2 : 4;
#pragma unroll
    for (int a = 0; a < 4; ++a) {
        float den = __shfl(acc[a][3], hg * 5 + 4);  // ch35 (pseudo-one) = denominator
        float rdn = 1.f / den;
        if (g == 0 && act && a < nh) {
            uint4 ov;
            ov.x = packbf(acc[a][0] * rdn, acc[a][1] * rdn);
            ov.y = packbf(acc[a][2] * rdn, acc[a][3] * rdn);
            ov.z = packbf(acc[a][4] * rdn, acc[a][5] * rdn);
            ov.w = packbf(acc[a][6] * rdn, acc[a][7] * rdn);
            stage[wid][(h0 + a) * 5 + sl] = ov;
        }
    }
    __syncthreads();
    // cooperative full-line NT burst: 4 nodes x 52 uint4 (last 2 = pad zeros)
    if (tid < 208) {
        const int nodeI = tid / 52, slot = tid - nodeI * 52;
        u32x4 val = {0, 0, 0, 0};
        if (slot < 50) {
            uint4 s4 = stage[nodeI][slot];
            val[0] = s4.x; val[1] = s4.y; val[2] = s4.z; val[3] = s4.w;
        }
        const size_t dd = (size_t)(blockIdx.x * 4 + nodeI);
        __builtin_nontemporal_store(val, (u32x4*)&aggx4[(dd * 52 + slot) * 4]);
    }
}

// ---------------- layer-1 projection: x2p = elu( aggx @ W1g ) ----------------
__global__ __launch_bounds__(256, 8) void k_gemm1b(const short* __restrict__ aggx,  // [N][416]
                                                   const short8* __restrict__ W1g,
                                                   unsigned short* __restrict__ x2p) {  // [N][352]
    const int lane = threadIdx.x & 63;
    const int wid = threadIdx.x >> 6;
    const int mtile = blockIdx.x * 4 + wid;
    if (mtile >= N_NODES / 16) return;
    const int c_lo = lane & 15, grp = lane >> 4;
    const int m0 = mtile * 16;
    const size_t abase = (size_t)(m0 + c_lo) * 416 + grp * 8;

#pragma unroll
    for (int h = 0; h < 10; ++h) {
        const short* ap = aggx + abase + h * 40;
        short8 a0 = __builtin_nontemporal_load(reinterpret_cast<const short8*>(ap));
        short8 a1 = __builtin_nontemporal_load(reinterpret_cast<const short8*>(ap + 32));  // k>=40 x B-zero
        f32x4 acc[3];
#pragma unroll
        for (int tt = 0; tt < 3; ++tt) acc[tt] = (f32x4){0.f, 0.f, 0.f, 0.f};
#pragma unroll
        for (int tt = 0; tt < 3; ++tt)
            acc[tt] = __builtin_amdgcn_mfma_f32_16x16x32_bf16(a0, W1g[((h * 2 + 0) * 3 + tt) * 64 + lane], acc[tt], 0, 0, 0);
#pragma unroll
        for (int tt = 0; tt < 3; ++tt)
            acc[tt] = __builtin_amdgcn_mfma_f32_16x16x32_bf16(a1, W1g[((h * 2 + 1) * 3 + tt) * 64 + lane], acc[tt], 0, 0, 0);
#pragma unroll
        for (int tt = 0; tt < 3; ++tt) {
            int c = tt * 16 + c_lo;
            if (c < C1) {
#pragma unroll
                for (int r = 0; r < 4; ++r) {
                    int node = m0 + grp * 4 + r;
                    float v = acc[tt][r];
                    v = (v > 0.f) ? v : expm1f(v);
                    x2p[(size_t)node * 352 + h * C1 + c] = bfbits(v);
                }
            }
        }
    }
    if (lane < 16) ((uint32*)x2p)[(size_t)(m0 + lane) * 176 + 175] = 0u;  // zero pad cols
}

// ---------------- layer 2 GEMM via MFMA, fused att dots ----------------
__global__ __launch_bounds__(256) void k_gemm2(const short* __restrict__ x2p,       // [N][352]
                                               const short8* __restrict__ W2f,
                                               const float* __restrict__ attS,
                                               const float* __restrict__ attD,
                                               unsigned short* __restrict__ h2b,    // [N][128]
                                               float* __restrict__ a_s2, float* __restrict__ a_d2) {
    const int lane = threadIdx.x & 63;
    const int wid = threadIdx.x >> 6;
    const int mtile = blockIdx.x * 4 + wid;
    if (mtile >= N_NODES / 16) return;
    const int c_lo = lane & 15, grp = lane >> 4;
    const int m0 = mtile * 16;
    const short* aptr = x2p + (size_t)(m0 + c_lo) * 352 + grp * 8;

    f32x4 acc[8];
#pragma unroll
    for (int t = 0; t < 8; ++t) acc[t] = (f32x4){0.f, 0.f, 0.f, 0.f};
#pragma unroll
    for (int kk = 0; kk < 11; ++kk) {
        short8 a = __builtin_nontemporal_load(reinterpret_cast<const short8*>(aptr + kk * 32));
#pragma unroll
        for (int t = 0; t < 8; ++t) {
            short8 b = W2f[(kk * 8 + t) * 64 + lane];
            acc[t] = __builtin_amdgcn_mfma_f32_16x16x32_bf16(a, b, acc[t], 0, 0, 0);
        }
    }
    float attSv[8], attDv[8];
#pragma unroll
    for (int t = 0; t < 8; ++t) {
        attSv[t] = attS[t * 16 + c_lo];
        attDv[t] = attD[t * 16 + c_lo];
    }
    float ps[4] = {0, 0, 0, 0}, pd[4] = {0, 0, 0, 0};
#pragma unroll
    for (int t = 0; t < 8; ++t)
#pragma unroll
        for (int r = 0; r < 4; ++r) {
            ps[r] = fmaf(acc[t][r], attSv[t], ps[r]);
            pd[r] = fmaf(acc[t][r], attDv[t], pd[r]);
        }
#pragma unroll
    for (int r = 0; r < 4; ++r) {
        int node = m0 + grp * 4 + r;
#pragma unroll
        for (int t = 0; t < 8; ++t) h2b[(size_t)node * C2 + t * 16 + c_lo] = bfbits(acc[t][r]);
    }
#pragma unroll
    for (int r = 0; r < 4; ++r) {
        float s = ps[r], dd = pd[r];
#pragma unroll
        for (int off = 1; off < 16; off <<= 1) {
            s += __shfl_xor(s, off);
            dd += __shfl_xor(dd, off);
        }
        if (c_lo == 0) {
            int node = m0 + grp * 4 + r;
            a_s2[node] = s;
            a_d2[node] = dd;
        }
    }
}

// ---------------- layer-2 aggregation -> out2 fp32 (bias+relu) ----------------
__global__ __launch_bounds__(256, 8) void k_agg2(const uint4* __restrict__ feat4,  // h2b [N][16]
                                                 const float* __restrict__ a_s,   // [N]
                                                 const float* __restrict__ a_d,
                                                 const int* __restrict__ offs,
                                                 const int* __restrict__ csr,
                                                 const float* __restrict__ b2,    // [128]
                                                 float* __restrict__ out2) {      // [N][128]
    const int lane = threadIdx.x & 63;
    const int wid = threadIdx.x >> 6;
    const int d = blockIdx.x * 4 + wid;
    const int o0 = offs[d];
    const int deg = offs[d + 1] - o0;
    const int total = deg + 1;
    const float add = a_d[d];
    const int g = lane >> 4, cl = lane & 15;

    float acc[8];
#pragma unroll
    for (int q = 0; q < 8; ++q) acc[q] = 0.f;
    float den = 0.f;

    for (int base = 0; base < total; base += 64) {
        const int i = base + lane;
        int s_mine = d;
        float e_mine = 0.f;
        if (i < total) {
            if (i < deg) s_mine = __builtin_nontemporal_load(csr + o0 + i);
            e_mine = __expf(lrelu(a_s[s_mine] + add));
            den += e_mine;
        }
        const int cnt = min(64, total - base);
        // prefetch depth 2 (4 edges per step)
        float aj0 = __shfl(e_mine, g);
        uint4 v0 = feat4[(size_t)__shfl(s_mine, g) * 16 + cl];
        float aj1 = 0.f;
        uint4 v1 = {0, 0, 0, 0};
        if (4 < cnt) {
            aj1 = __shfl(e_mine, 4 + g);
            v1 = feat4[(size_t)__shfl(s_mine, 4 + g) * 16 + cl];
        }
        for (int jb = 0; jb < cnt; jb += 4) {
            uint4 v = v0;
            float a = aj0;
            v0 = v1; aj0 = aj1;
            if (jb + 8 < cnt) {
                int ni = jb + 8 + g;
                aj1 = __shfl(e_mine, ni);
                v1 = feat4[(size_t)__shfl(s_mine, ni) * 16 + cl];
            }
            acc[0] = fmaf(a, bflo(v.x), acc[0]);
            acc[1] = fmaf(a, bfhi(v.x), acc[1]);
            acc[2] = fmaf(a, bflo(v.y), acc[2]);
            acc[3] = fmaf(a, bfhi(v.y), acc[3]);
            acc[4] = fmaf(a, bflo(v.z), acc[4]);
            acc[5] = fmaf(a, bfhi(v.z), acc[5]);
            acc[6] = fmaf(a, bflo(v.w), acc[6]);
            acc[7] = fmaf(a, bfhi(v.w), acc[7]);
        }
    }
#pragma unroll
    for (int q = 0; q < 8; ++q) {
        acc[q] += __shfl_xor(acc[q], 16);
        acc[q] += __shfl_xor(acc[q], 32);
    }
#pragma unroll
    for (int off = 32; off > 0; off >>= 1) den += __shfl_xor(den, off);

    if (lane < 16) {
        const float rden = 1.f / den;
        const float4* bp = (const float4*)(b2 + 8 * cl);
        float4 b0 = bp[0], b1 = bp[1];
        f32x4 o0v, o1v;
        o0v[0] = fmaxf(acc[0] * rden + b0.x, 0.f);
        o0v[1] = fmaxf(acc[1] * rden + b0.y, 0.f);
        o0v[2] = fmaxf(acc[2] * rden + b0.z, 0.f);
        o0v[3] = fmaxf(acc[3] * rden + b0.w, 0.f);
        o1v[0] = fmaxf(acc[4] * rden + b1.x, 0.f);
        o1v[1] = fmaxf(acc[5] * rden + b1.y, 0.f);
        o1v[2] = fmaxf(acc[6] * rden + b1.z, 0.f);
        o1v[3] = fmaxf(acc[7] * rden + b1.w, 0.f);
        f32x4* op = (f32x4*)(out2 + (size_t)d * C2 + 8 * cl);
        __builtin_nontemporal_store(o0v, op);   // full-line: 16 lanes x 16B contiguous
        __builtin_nontemporal_store(o1v, op + 1);
    }
}

// ---------------- pooling: sorted-batch run-length max ----------------
__global__ __launch_bounds__(128) void k_pool(const float* __restrict__ out2,
                                              const int* __restrict__ batch,
                                              float* __restrict__ pooled) {
    const int c = threadIdx.x;
    const int n0 = blockIdx.x * 50;
    const int n1 = min(n0 + 50, N_NODES);
    int curB = batch[n0];
    float curM = 0.f;
    float v = __builtin_nontemporal_load(out2 + (size_t)n0 * C2 + c);
    for (int n = n0; n < n1; ++n) {
        float cur = v;
        int b = batch[n];
        if (n + 1 < n1) v = __builtin_nontemporal_load(out2 + (size_t)(n + 1) * C2 + c);
        if (b != curB) {
            atomicMax((int*)&pooled[curB * C2 + c], __float_as_int(curM));
            curB = b;
            curM = cur;
        } else {
            curM = fmaxf(curM, cur);
        }
    }
    atomicMax((int*)&pooled[curB * C2 + c], __float_as_int(curM));
}

// ---------------- dense head ----------------
__global__ __launch_bounds__(128) void k_head(const float* __restrict__ pooled,
                                              const float* __restrict__ Wg,
                                              const float* __restrict__ bg,
                                              const float* __restrict__ Wo,
                                              const float* __restrict__ bo,
                                              float* __restrict__ out) {
    __shared__ float p[C2];
    __shared__ float wsum[2];
    const int g = blockIdx.x;
    const int tid = threadIdx.x;
    p[tid] = pooled[g * C2 + tid];
    __syncthreads();
    float acc = bg[tid];
#pragma unroll 8
    for (int k = 0; k < C2; ++k) acc = fmaf(p[k], Wg[k * C2 + tid], acc);
    float z = fmaxf(acc, 0.f);
    float prod = z * Wo[tid];
#pragma unroll
    for (int off = 32; off; off >>= 1) prod += __shfl_down(prod, off);
    if ((tid & 63) == 0) wsum[tid >> 6] = prod;
    __syncthreads();
    if (tid == 0) out[g] = wsum[0] + wsum[1] + bo[0];
}

extern "C" void kernel_launch(void* const* d_in, const int* in_sizes, int n_in,
                              void* d_out, int out_size, void* d_ws, size_t ws_size,
                              hipStream_t stream) {
    const float* x        = (const float*)d_in[0];
    const int*   ei       = (const int*)d_in[1];
    const int*   batch    = (const int*)d_in[2];
    const float* W1       = (const float*)d_in[3];
    const float* att_src1 = (const float*)d_in[4];
    const float* att_dst1 = (const float*)d_in[5];
    const float* b1       = (const float*)d_in[6];
    const float* W2       = (const float*)d_in[7];
    const float* att_src2 = (const float*)d_in[8];
    const float* att_dst2 = (const float*)d_in[9];
    const float* b2       = (const float*)d_in[10];
    const float* Wg       = (const float*)d_in[11];
    const float* bg       = (const float*)d_in[12];
    const float* Wo       = (const float*)d_in[13];
    const float* bo       = (const float*)d_in[14];
    const int* src = ei;
    const int* dst = ei + N_EDGES;

    char* ws = (char*)d_ws;
    size_t off = 0;
    auto alloc = [&](size_t bytes) -> char* {
        char* p = ws + off;
        off = (off + bytes + 255) & ~(size_t)255;
        return p;
    };
    int*    deg    = (int*)alloc((size_t)N_NODES * 4);
    int*    offs   = (int*)alloc((size_t)(N_NODES + 1) * 4);
    int*    cursor = (int*)alloc((size_t)N_NODES * 4);
    int*    csr    = (int*)alloc((size_t)N_EDGES * 4);
    int*    bsum   = (int*)alloc((size_t)NB256 * 4);
    int*    bpre   = (int*)alloc((size_t)NB256 * 4);
    float*  a_s1   = (float*)alloc((size_t)N_NODES * H1 * 4);
    float*  a_d1   = (float*)alloc((size_t)N_NODES * H1 * 4);
    float*  a_s2   = (float*)alloc((size_t)N_NODES * 4);
    float*  a_d2   = (float*)alloc((size_t)N_NODES * 4);
    float*  pooled = (float*)alloc((size_t)N_GRAPHS * C2 * 4);
    float*  fold   = (float*)alloc((size_t)700 * 4);
    uint32* xbf    = (uint32*)alloc((size_t)N_NODES * 20 * 4);        // [N][40] bf16
    uint32* aggx   = (uint32*)alloc((size_t)N_NODES * 832 + 1024);    // [N][416] bf16 (832B rows)
    uint32* x2p    = (uint32*)alloc((size_t)N_NODES * 176 * 4);       // [N][352] bf16
    unsigned short* h2b = (unsigned short*)alloc((size_t)N_NODES * C2 * 2);
    uint32* W1g    = (uint32*)alloc((size_t)10 * 2 * 3 * 64 * 16);
    uint32* W2f    = (uint32*)alloc((size_t)11 * 8 * 64 * 16);
    float*  out2   = (float*)aggx;  // aggx dead after k_gemm1b; 25.6 MB fits in 41.6 MB

    hipMemsetAsync(deg, 0, (size_t)N_NODES * 4, stream);
    hipMemsetAsync(pooled, 0, (size_t)N_GRAPHS * C2 * 4, stream);

    k_count<<<(N_EDGES + 255) / 256, 256, 0, stream>>>(dst, deg);
    k_bsum<<<NB256, 256, 0, stream>>>(deg, bsum);
    k_bscan<<<1, 256, 0, stream>>>(bsum, bpre);
    k_boffs<<<NB256, 256, 0, stream>>>(deg, bpre, offs, cursor);
    k_fill<<<(N_EDGES + 255) / 256, 256, 0, stream>>>(src, dst, cursor, csr);

    k_prep<<<XB + 3 + 15 + 22, 256, 0, stream>>>(x, W1, att_src1, att_dst1, b1, W2,
                                                 xbf, fold, W1g, W2f);
    k_att1<<<(N_NODES * 20 + 255) / 256, 256, 0, stream>>>(x, fold, a_s1, a_d1);

    k_aggx<<<N_NODES / 4, 256, 0, stream>>>((const uint4*)xbf, a_s1, a_d1, offs, csr, aggx);

    k_gemm1b<<<(N_NODES / 16 + 3) / 4, 256, 0, stream>>>((const short*)aggx, (const short8*)W1g,
                                                         (unsigned short*)x2p);

    k_gemm2<<<(N_NODES / 16 + 3) / 4, 256, 0, stream>>>((const short*)x2p, (const short8*)W2f,
                                                        att_src2, att_dst2, h2b, a_s2, a_d2);

    k_agg2<<<N_NODES / 4, 256, 0, stream>>>((const uint4*)h2b, a_s2, a_d2, offs, csr, b2, out2);

    k_pool<<<(N_NODES + 49) / 50, 128, 0, stream>>>(out2, batch, pooled);

    k_head<<<N_GRAPHS, 128, 0, stream>>>(pooled, Wg, bg, Wo, bo, (float*)d_out);
}

// Round 10
// 367.539 us; speedup vs baseline: 1.2528x; 1.1145x over previous
//
#include <hip/hip_runtime.h>
#include <hip/hip_bf16.h>
#include <cmath>

#define N_NODES 50000
#define N_EDGES 800000
#define N_GRAPHS 1024
#define F_IN 35
#define H1 10
#define C1 35
#define HC1 350
#define C2 128
#define NB256 196   // ceil(N_NODES/256)

typedef unsigned int uint32;
typedef __attribute__((ext_vector_type(8))) short short8;
typedef __attribute__((ext_vector_type(4))) float f32x4;

static __device__ __forceinline__ float bflo(uint32 u) { return __uint_as_float(u << 16); }
static __device__ __forceinline__ float bfhi(uint32 u) { return __uint_as_float(u & 0xffff0000u); }
static __device__ __forceinline__ unsigned short bfbits(float f) {
    return __builtin_bit_cast(unsigned short, __float2bfloat16(f));
}
static __device__ __forceinline__ uint32 packbf(float a, float b) {
    return ((uint32)bfbits(b) << 16) | (uint32)bfbits(a);
}
static __device__ __forceinline__ float lrelu(float e) { return (e > 0.f) ? e : 0.2f * e; }

// ---------------- CSR: count ----------------
__global__ void k_count(const int* __restrict__ dst, int* __restrict__ deg) {
    int e = blockIdx.x * blockDim.x + threadIdx.x;
    if (e < N_EDGES) atomicAdd(&deg[dst[e]], 1);
}

// ---------------- CSR: hierarchical scan ----------------
__global__ __launch_bounds__(256) void k_bsum(const int* __restrict__ deg, int* __restrict__ bsum) {
    const int i = blockIdx.x * 256 + threadIdx.x;
    int v = (i < N_NODES) ? deg[i] : 0;
#pragma unroll
    for (int off = 32; off; off >>= 1) v += __shfl_xor(v, off);
    __shared__ int ws[4];
    if ((threadIdx.x & 63) == 0) ws[threadIdx.x >> 6] = v;
    __syncthreads();
    if (threadIdx.x == 0) bsum[blockIdx.x] = ws[0] + ws[1] + ws[2] + ws[3];
}

__global__ __launch_bounds__(256) void k_bscan(const int* __restrict__ bsum, int* __restrict__ bpre) {
    __shared__ int buf[256];
    const int t = threadIdx.x;
    int v = (t < NB256) ? bsum[t] : 0;
    buf[t] = v;
    __syncthreads();
    for (int off = 1; off < 256; off <<= 1) {
        int u = (t >= off) ? buf[t - off] : 0;
        __syncthreads();
        buf[t] += u;
        __syncthreads();
    }
    if (t < NB256) bpre[t] = buf[t] - v;  // exclusive
}

__global__ __launch_bounds__(256) void k_boffs(const int* __restrict__ deg,
                                               const int* __restrict__ bpre,
                                               int* __restrict__ offs, int* __restrict__ cursor) {
    const int b = blockIdx.x, t = threadIdx.x;
    const int i = b * 256 + t;
    const int lane = t & 63, wid = t >> 6;
    int v = (i < N_NODES) ? deg[i] : 0;
    int s = v;
#pragma unroll
    for (int off = 1; off < 64; off <<= 1) {
        int u = __shfl_up(s, off);
        if (lane >= off) s += u;
    }
    __shared__ int wsum[4];
    if (lane == 63) wsum[wid] = s;
    __syncthreads();
    int wbase = 0;
    for (int w = 0; w < wid; ++w) wbase += wsum[w];
    int excl = bpre[b] + wbase + s - v;
    if (i < N_NODES) { offs[i] = excl; cursor[i] = excl; }
    if (i == 0) offs[N_NODES] = N_EDGES;
}

__global__ void k_fill(const int* __restrict__ src, const int* __restrict__ dst,
                       int* __restrict__ cursor, int* __restrict__ csr) {
    int e = blockIdx.x * blockDim.x + threadIdx.x;
    if (e < N_EDGES) {
        int p = atomicAdd(&cursor[dst[e]], 1);
        csr[p] = src[e];
    }
}

// ---------------- fused prep ----------------
#define XB ((N_NODES * 5 + 255) / 256)
__global__ __launch_bounds__(256) void k_prep(const float* __restrict__ x,
                                              const float* __restrict__ W1,
                                              const float* __restrict__ attS1,
                                              const float* __restrict__ attD1,
                                              const float* __restrict__ b1,
                                              const float* __restrict__ W2,
                                              uint32* __restrict__ xbf,
                                              float* __restrict__ fold,
                                              uint32* __restrict__ W1g,
                                              uint32* __restrict__ W2f) {
    const int b = blockIdx.x, t = threadIdx.x;
    if (b < XB) {
        int idx = b * 256 + t;
        if (idx >= N_NODES * 5) return;
        int n = idx / 5, s = idx - n * 5;
        uint32 o[4];
#pragma unroll
        for (int p = 0; p < 4; ++p) {
            int ch0 = s * 8 + 2 * p, ch1 = ch0 + 1;
            float a = (ch0 < F_IN) ? x[(size_t)n * F_IN + ch0] : (ch0 == 35 ? 1.f : 0.f);
            float bb = (ch1 < F_IN) ? x[(size_t)n * F_IN + ch1] : (ch1 == 35 ? 1.f : 0.f);
            o[p] = packbf(a, bb);
        }
        uint32* d = xbf + (size_t)idx * 4;
        d[0] = o[0]; d[1] = o[1]; d[2] = o[2]; d[3] = o[3];
    } else if (b < XB + 3) {
        int idx = (b - XB) * 256 + t;
        if (idx >= 700) return;
        int k = idx / 20, o = idx - k * 20;
        int h = (o < 10) ? o : o - 10;
        const float* att = (o < 10) ? attS1 : attD1;
        float s = 0.f;
        for (int c = 0; c < C1; ++c)
            s = fmaf(W1[k * HC1 + h * C1 + c], att[h * C1 + c], s);
        fold[k * 20 + o] = s;
    } else if (b < XB + 3 + 15) {
        int idx = (b - XB - 3) * 256 + t;
        if (idx >= 10 * 2 * 3 * 64) return;
        int lane = idx & 63;
        int rest = idx >> 6;
        int tt = rest % 3;
        int rest2 = rest / 3;
        int kk = rest2 & 1;
        int h = rest2 >> 1;
        int c = tt * 16 + (lane & 15);
        int k0 = kk * 32 + (lane >> 4) * 8;
        uint32 o[4];
#pragma unroll
        for (int jj = 0; jj < 4; ++jj) {
            float v[2];
#pragma unroll
            for (int half = 0; half < 2; ++half) {
                int k = k0 + 2 * jj + half;
                float val = 0.f;
                if (c < C1) {
                    if (k < F_IN) val = W1[k * HC1 + h * C1 + c];
                    else if (k == 35) val = b1[h * C1 + c];
                }
                v[half] = val;
            }
            o[jj] = packbf(v[0], v[1]);
        }
        uint32* d = W1g + (size_t)idx * 4;
        d[0] = o[0]; d[1] = o[1]; d[2] = o[2]; d[3] = o[3];
    } else {
        int idx = (b - XB - 3 - 15) * 256 + t;
        if (idx >= 11 * 8 * 64) return;
        int lane = idx & 63;
        int tt = (idx >> 6) & 7;
        int kk = idx >> 9;
        int c = tt * 16 + (lane & 15);
        int k0 = kk * 32 + (lane >> 4) * 8;
        uint32 o[4];
#pragma unroll
        for (int jj = 0; jj < 4; ++jj) {
            int ka = k0 + 2 * jj, kb = ka + 1;
            float va = (ka < HC1) ? W2[ka * C2 + c] : 0.f;
            float vb = (kb < HC1) ? W2[kb * C2 + c] : 0.f;
            o[jj] = packbf(va, vb);
        }
        uint32* d = W2f + (size_t)idx * 4;
        d[0] = o[0]; d[1] = o[1]; d[2] = o[2]; d[3] = o[3];
    }
}

// ---------------- attention pre-dots: a_s1/a_d1 = x @ fold (fp32) ----------------
__global__ __launch_bounds__(256) void k_att1(const float* __restrict__ x,
                                              const float* __restrict__ fold,
                                              float* __restrict__ a_s1,
                                              float* __restrict__ a_d1) {
    int idx = blockIdx.x * 256 + threadIdx.x;
    if (idx >= N_NODES * 20) return;
    int n = idx / 20, o = idx - n * 20;
    const float* xr = x + (size_t)n * F_IN;
    float acc = 0.f;
#pragma unroll
    for (int k = 0; k < F_IN; ++k) acc = fmaf(xr[k], fold[k * 20 + o], acc);
    if (o < 10) a_s1[n * 10 + o] = acc;
    else        a_d1[n * 10 + (o - 10)] = acc;
}

// ---------------- layer-1 aggregation in INPUT space ----------------
__global__ __launch_bounds__(256, 8) void k_aggx(const uint4* __restrict__ xbf4,  // [N][5]
                                                 const float* __restrict__ a_s,   // [N][10]
                                                 const float* __restrict__ a_d,   // [N][10]
                                                 const int* __restrict__ offs,
                                                 const int* __restrict__ csr,
                                                 uint4* __restrict__ aggx4) {     // [N*10][5]
    __shared__ float al[4][10][68];
    __shared__ float addl[4][10];
    __shared__ int totmax[4];
    const int tid = threadIdx.x, lane = tid & 63, wid = tid >> 6;
    const int d = blockIdx.x * 4 + wid;
    const int o0 = offs[d];
    const int deg = offs[d + 1] - o0;
    const int total = deg + 1;  // self-loop as edge 'deg'
    const int g = lane >> 4, u = lane & 15;
    const int hg = (u >= 10) ? 2 : ((u >= 5) ? 1 : 0);
    const int sl = u - hg * 5;
    const bool act = (u < 15);
    const int h0 = hg * 4;

    if (lane < 10) addl[wid][lane] = a_d[(size_t)d * 10 + lane];
    if (lane < 4) {
#pragma unroll
        for (int h = 0; h < 10; ++h) al[wid][h][64 + lane] = 0.f;  // jj-overrun pads
    }
    if (lane == 0) totmax[wid] = total;
    __syncthreads();
    const int tmx = max(max(totmax[0], totmax[1]), max(totmax[2], totmax[3]));
    const int rounds = (tmx + 63) >> 6;

    float acc[4][8];
#pragma unroll
    for (int a = 0; a < 4; ++a)
#pragma unroll
        for (int q = 0; q < 8; ++q) acc[a][q] = 0.f;

    for (int rb = 0; rb < rounds; ++rb) {
        const int base = rb << 6;
        const int i = base + lane;
        int s_mine = d;
        if (i < total) {
            if (i < deg) s_mine = __builtin_nontemporal_load(csr + o0 + i);
            const float2* ap = (const float2*)(a_s + (size_t)s_mine * 10);
            float2 p0 = ap[0], p1 = ap[1], p2 = ap[2], p3 = ap[3], p4 = ap[4];
            al[wid][0][lane] = __expf(lrelu(p0.x + addl[wid][0]));
            al[wid][1][lane] = __expf(lrelu(p0.y + addl[wid][1]));
            al[wid][2][lane] = __expf(lrelu(p1.x + addl[wid][2]));
            al[wid][3][lane] = __expf(lrelu(p1.y + addl[wid][3]));
            al[wid][4][lane] = __expf(lrelu(p2.x + addl[wid][4]));
            al[wid][5][lane] = __expf(lrelu(p2.y + addl[wid][5]));
            al[wid][6][lane] = __expf(lrelu(p3.x + addl[wid][6]));
            al[wid][7][lane] = __expf(lrelu(p3.y + addl[wid][7]));
            al[wid][8][lane] = __expf(lrelu(p4.x + addl[wid][8]));
            al[wid][9][lane] = __expf(lrelu(p4.y + addl[wid][9]));
        } else {
#pragma unroll
            for (int h = 0; h < 10; ++h) al[wid][h][lane] = 0.f;
        }
        __syncthreads();
        const int cnt = min(64, total - base);
        if (cnt > 0) {
            // prefetch depth 2 (4 edges per step)
            uint4 v0 = {0, 0, 0, 0}, v1 = {0, 0, 0, 0};
            {
                int s0 = __shfl(s_mine, g);
                if (act) v0 = xbf4[(size_t)s0 * 5 + sl];
            }
            if (4 < cnt) {
                int s1 = __shfl(s_mine, 4 + g);
                if (act) v1 = xbf4[(size_t)s1 * 5 + sl];
            }
            for (int jb = 0; jb < cnt; jb += 4) {
                uint4 w = v0;
                v0 = v1;
                const int jj = jb + g;  // al[.][.][jj]==0 for jj>=cnt (incl. pads 64..67)
                if (jb + 8 < cnt) {
                    int sn = __shfl(s_mine, jb + 8 + g);
                    if (act) v1 = xbf4[(size_t)sn * 5 + sl];
                }
                float f0 = bflo(w.x), f1 = bfhi(w.x), f2 = bflo(w.y), f3 = bfhi(w.y);
                float f4 = bflo(w.z), f5 = bfhi(w.z), f6 = bflo(w.w), f7 = bfhi(w.w);
#pragma unroll
                for (int a = 0; a < 4; ++a) {
                    const int hidx = min(h0 + a, 9);  // hg2 a>=2 dead (clamped, not stored)
                    const float aj = al[wid][hidx][jj];
                    acc[a][0] = fmaf(aj, f0, acc[a][0]);
                    acc[a][1] = fmaf(aj, f1, acc[a][1]);
                    acc[a][2] = fmaf(aj, f2, acc[a][2]);
                    acc[a][3] = fmaf(aj, f3, acc[a][3]);
                    acc[a][4] = fmaf(aj, f4, acc[a][4]);
                    acc[a][5] = fmaf(aj, f5, acc[a][5]);
                    acc[a][6] = fmaf(aj, f6, acc[a][6]);
                    acc[a][7] = fmaf(aj, f7, acc[a][7]);
                }
            }
        }
        __syncthreads();
    }
    // combine the 4 edge-groups
#pragma unroll
    for (int a = 0; a < 4; ++a)
#pragma unroll
        for (int q = 0; q < 8; ++q) {
            acc[a][q] += __shfl_xor(acc[a][q], 16);
            acc[a][q] += __shfl_xor(acc[a][q], 32);
        }
    const int nh = (hg == 2) ? 2 : 4;
#pragma unroll
    for (int a = 0; a < 4; ++a) {
        float den = __shfl(acc[a][3], hg * 5 + 4);  // ch35 (pseudo-one) = denominator
        float rdn = 1.f / den;
        if (g == 0 && act && a < nh) {
            uint4 ov;
            ov.x = packbf(acc[a][0] * rdn, acc[a][1] * rdn);
            ov.y = packbf(acc[a][2] * rdn, acc[a][3] * rdn);
            ov.z = packbf(acc[a][4] * rdn, acc[a][5] * rdn);
            ov.w = packbf(acc[a][6] * rdn, acc[a][7] * rdn);
            aggx4[((size_t)d * 10 + h0 + a) * 5 + sl] = ov;  // plain cached store (NT amplifies!)
        }
    }
}

// ---------------- layer-1 projection: x2p = elu( aggx @ W1g ) ----------------
__global__ __launch_bounds__(256, 8) void k_gemm1b(const short* __restrict__ aggx,  // [N*10][40]
                                                   const short8* __restrict__ W1g,
                                                   unsigned short* __restrict__ x2p) {  // [N][352]
    const int lane = threadIdx.x & 63;
    const int wid = threadIdx.x >> 6;
    const int mtile = blockIdx.x * 4 + wid;
    if (mtile >= N_NODES / 16) return;
    const int c_lo = lane & 15, grp = lane >> 4;
    const int m0 = mtile * 16;
    const size_t abase = (size_t)(m0 + c_lo) * 400 + grp * 8;

#pragma unroll
    for (int h = 0; h < 10; ++h) {
        const short* ap = aggx + abase + h * 40;
        short8 a0 = *reinterpret_cast<const short8*>(ap);
        short8 a1 = *reinterpret_cast<const short8*>(ap + 32);  // k>=40 garbage x B-zero = 0
        f32x4 acc[3];
#pragma unroll
        for (int tt = 0; tt < 3; ++tt) acc[tt] = (f32x4){0.f, 0.f, 0.f, 0.f};
#pragma unroll
        for (int tt = 0; tt < 3; ++tt)
            acc[tt] = __builtin_amdgcn_mfma_f32_16x16x32_bf16(a0, W1g[((h * 2 + 0) * 3 + tt) * 64 + lane], acc[tt], 0, 0, 0);
#pragma unroll
        for (int tt = 0; tt < 3; ++tt)
            acc[tt] = __builtin_amdgcn_mfma_f32_16x16x32_bf16(a1, W1g[((h * 2 + 1) * 3 + tt) * 64 + lane], acc[tt], 0, 0, 0);
#pragma unroll
        for (int tt = 0; tt < 3; ++tt) {
            int c = tt * 16 + c_lo;
            if (c < C1) {
#pragma unroll
                for (int r = 0; r < 4; ++r) {
                    int node = m0 + grp * 4 + r;
                    float v = acc[tt][r];
                    v = (v > 0.f) ? v : expm1f(v);
                    x2p[(size_t)node * 352 + h * C1 + c] = bfbits(v);
                }
            }
        }
    }
    if (lane < 16) ((uint32*)x2p)[(size_t)(m0 + lane) * 176 + 175] = 0u;  // zero pad cols
}

// ---------------- layer 2 GEMM via MFMA, fused att dots ----------------
__global__ __launch_bounds__(256) void k_gemm2(const short* __restrict__ x2p,       // [N][352]
                                               const short8* __restrict__ W2f,
                                               const float* __restrict__ attS,
                                               const float* __restrict__ attD,
                                               unsigned short* __restrict__ h2b,    // [N][128]
                                               float* __restrict__ a_s2, float* __restrict__ a_d2) {
    const int lane = threadIdx.x & 63;
    const int wid = threadIdx.x >> 6;
    const int mtile = blockIdx.x * 4 + wid;
    if (mtile >= N_NODES / 16) return;
    const int c_lo = lane & 15, grp = lane >> 4;
    const int m0 = mtile * 16;
    const short* aptr = x2p + (size_t)(m0 + c_lo) * 352 + grp * 8;

    f32x4 acc[8];
#pragma unroll
    for (int t = 0; t < 8; ++t) acc[t] = (f32x4){0.f, 0.f, 0.f, 0.f};
#pragma unroll
    for (int kk = 0; kk < 11; ++kk) {
        short8 a = *reinterpret_cast<const short8*>(aptr + kk * 32);
#pragma unroll
        for (int t = 0; t < 8; ++t) {
            short8 b = W2f[(kk * 8 + t) * 64 + lane];
            acc[t] = __builtin_amdgcn_mfma_f32_16x16x32_bf16(a, b, acc[t], 0, 0, 0);
        }
    }
    float attSv[8], attDv[8];
#pragma unroll
    for (int t = 0; t < 8; ++t) {
        attSv[t] = attS[t * 16 + c_lo];
        attDv[t] = attD[t * 16 + c_lo];
    }
    float ps[4] = {0, 0, 0, 0}, pd[4] = {0, 0, 0, 0};
#pragma unroll
    for (int t = 0; t < 8; ++t)
#pragma unroll
        for (int r = 0; r < 4; ++r) {
            ps[r] = fmaf(acc[t][r], attSv[t], ps[r]);
            pd[r] = fmaf(acc[t][r], attDv[t], pd[r]);
        }
#pragma unroll
    for (int r = 0; r < 4; ++r) {
        int node = m0 + grp * 4 + r;
#pragma unroll
        for (int t = 0; t < 8; ++t) h2b[(size_t)node * C2 + t * 16 + c_lo] = bfbits(acc[t][r]);
    }
#pragma unroll
    for (int r = 0; r < 4; ++r) {
        float s = ps[r], dd = pd[r];
#pragma unroll
        for (int off = 1; off < 16; off <<= 1) {
            s += __shfl_xor(s, off);
            dd += __shfl_xor(dd, off);
        }
        if (c_lo == 0) {
            int node = m0 + grp * 4 + r;
            a_s2[node] = s;
            a_d2[node] = dd;
        }
    }
}

// ---------------- layer-2 aggregation -> out2 fp32 (bias+relu) ----------------
__global__ __launch_bounds__(256, 8) void k_agg2(const uint4* __restrict__ feat4,  // h2b [N][16]
                                                 const float* __restrict__ a_s,   // [N]
                                                 const float* __restrict__ a_d,
                                                 const int* __restrict__ offs,
                                                 const int* __restrict__ csr,
                                                 const float* __restrict__ b2,    // [128]
                                                 float* __restrict__ out2) {      // [N][128]
    const int lane = threadIdx.x & 63;
    const int wid = threadIdx.x >> 6;
    const int d = blockIdx.x * 4 + wid;
    const int o0 = offs[d];
    const int deg = offs[d + 1] - o0;
    const int total = deg + 1;
    const float add = a_d[d];
    const int g = lane >> 4, cl = lane & 15;

    float acc[8];
#pragma unroll
    for (int q = 0; q < 8; ++q) acc[q] = 0.f;
    float den = 0.f;

    for (int base = 0; base < total; base += 64) {
        const int i = base + lane;
        int s_mine = d;
        float e_mine = 0.f;
        if (i < total) {
            if (i < deg) s_mine = __builtin_nontemporal_load(csr + o0 + i);
            e_mine = __expf(lrelu(a_s[s_mine] + add));
            den += e_mine;
        }
        const int cnt = min(64, total - base);
        // prefetch depth 2 (4 edges per step)
        float aj0 = __shfl(e_mine, g);
        uint4 v0 = feat4[(size_t)__shfl(s_mine, g) * 16 + cl];
        float aj1 = 0.f;
        uint4 v1 = {0, 0, 0, 0};
        if (4 < cnt) {
            aj1 = __shfl(e_mine, 4 + g);
            v1 = feat4[(size_t)__shfl(s_mine, 4 + g) * 16 + cl];
        }
        for (int jb = 0; jb < cnt; jb += 4) {
            uint4 v = v0;
            float a = aj0;
            v0 = v1; aj0 = aj1;
            if (jb + 8 < cnt) {
                int ni = jb + 8 + g;
                aj1 = __shfl(e_mine, ni);
                v1 = feat4[(size_t)__shfl(s_mine, ni) * 16 + cl];
            }
            acc[0] = fmaf(a, bflo(v.x), acc[0]);
            acc[1] = fmaf(a, bfhi(v.x), acc[1]);
            acc[2] = fmaf(a, bflo(v.y), acc[2]);
            acc[3] = fmaf(a, bfhi(v.y), acc[3]);
            acc[4] = fmaf(a, bflo(v.z), acc[4]);
            acc[5] = fmaf(a, bfhi(v.z), acc[5]);
            acc[6] = fmaf(a, bflo(v.w), acc[6]);
            acc[7] = fmaf(a, bfhi(v.w), acc[7]);
        }
    }
#pragma unroll
    for (int q = 0; q < 8; ++q) {
        acc[q] += __shfl_xor(acc[q], 16);
        acc[q] += __shfl_xor(acc[q], 32);
    }
#pragma unroll
    for (int off = 32; off > 0; off >>= 1) den += __shfl_xor(den, off);

    if (lane < 16) {
        const float rden = 1.f / den;
        const float4* bp = (const float4*)(b2 + 8 * cl);
        float4 b0 = bp[0], b1 = bp[1];
        float4 o0v, o1v;
        o0v.x = fmaxf(acc[0] * rden + b0.x, 0.f);
        o0v.y = fmaxf(acc[1] * rden + b0.y, 0.f);
        o0v.z = fmaxf(acc[2] * rden + b0.z, 0.f);
        o0v.w = fmaxf(acc[3] * rden + b0.w, 0.f);
        o1v.x = fmaxf(acc[4] * rden + b1.x, 0.f);
        o1v.y = fmaxf(acc[5] * rden + b1.y, 0.f);
        o1v.z = fmaxf(acc[6] * rden + b1.z, 0.f);
        o1v.w = fmaxf(acc[7] * rden + b1.w, 0.f);
        float4* op = (float4*)(out2 + (size_t)d * C2 + 8 * cl);
        op[0] = o0v;   // plain cached stores (NT amplifies writes ~10x on this HW)
        op[1] = o1v;
    }
}

// ---------------- pooling: sorted-batch run-length max ----------------
__global__ __launch_bounds__(128) void k_pool(const float* __restrict__ out2,
                                              const int* __restrict__ batch,
                                              float* __restrict__ pooled) {
    const int c = threadIdx.x;
    const int n0 = blockIdx.x * 50;
    const int n1 = min(n0 + 50, N_NODES);
    int curB = batch[n0];
    float curM = 0.f;
    float v = out2[(size_t)n0 * C2 + c];
    for (int n = n0; n < n1; ++n) {
        float cur = v;
        int b = batch[n];
        if (n + 1 < n1) v = out2[(size_t)(n + 1) * C2 + c];
        if (b != curB) {
            atomicMax((int*)&pooled[curB * C2 + c], __float_as_int(curM));
            curB = b;
            curM = cur;
        } else {
            curM = fmaxf(curM, cur);
        }
    }
    atomicMax((int*)&pooled[curB * C2 + c], __float_as_int(curM));
}

// ---------------- dense head ----------------
__global__ __launch_bounds__(128) void k_head(const float* __restrict__ pooled,
                                              const float* __restrict__ Wg,
                                              const float* __restrict__ bg,
                                              const float* __restrict__ Wo,
                                              const float* __restrict__ bo,
                                              float* __restrict__ out) {
    __shared__ float p[C2];
    __shared__ float wsum[2];
    const int g = blockIdx.x;
    const int tid = threadIdx.x;
    p[tid] = pooled[g * C2 + tid];
    __syncthreads();
    float acc = bg[tid];
#pragma unroll 8
    for (int k = 0; k < C2; ++k) acc = fmaf(p[k], Wg[k * C2 + tid], acc);
    float z = fmaxf(acc, 0.f);
    float prod = z * Wo[tid];
#pragma unroll
    for (int off = 32; off; off >>= 1) prod += __shfl_down(prod, off);
    if ((tid & 63) == 0) wsum[tid >> 6] = prod;
    __syncthreads();
    if (tid == 0) out[g] = wsum[0] + wsum[1] + bo[0];
}

extern "C" void kernel_launch(void* const* d_in, const int* in_sizes, int n_in,
                              void* d_out, int out_size, void* d_ws, size_t ws_size,
                              hipStream_t stream) {
    const float* x        = (const float*)d_in[0];
    const int*   ei       = (const int*)d_in[1];
    const int*   batch    = (const int*)d_in[2];
    const float* W1       = (const float*)d_in[3];
    const float* att_src1 = (const float*)d_in[4];
    const float* att_dst1 = (const float*)d_in[5];
    const float* b1       = (const float*)d_in[6];
    const float* W2       = (const float*)d_in[7];
    const float* att_src2 = (const float*)d_in[8];
    const float* att_dst2 = (const float*)d_in[9];
    const float* b2       = (const float*)d_in[10];
    const float* Wg       = (const float*)d_in[11];
    const float* bg       = (const float*)d_in[12];
    const float* Wo       = (const float*)d_in[13];
    const float* bo       = (const float*)d_in[14];
    const int* src = ei;
    const int* dst = ei + N_EDGES;

    char* ws = (char*)d_ws;
    size_t off = 0;
    auto alloc = [&](size_t bytes) -> char* {
        char* p = ws + off;
        off = (off + bytes + 255) & ~(size_t)255;
        return p;
    };
    int*    deg    = (int*)alloc((size_t)N_NODES * 4);
    int*    offs   = (int*)alloc((size_t)(N_NODES + 1) * 4);
    int*    cursor = (int*)alloc((size_t)N_NODES * 4);
    int*    csr    = (int*)alloc((size_t)N_EDGES * 4);
    int*    bsum   = (int*)alloc((size_t)NB256 * 4);
    int*    bpre   = (int*)alloc((size_t)NB256 * 4);
    float*  a_s1   = (float*)alloc((size_t)N_NODES * H1 * 4);
    float*  a_d1   = (float*)alloc((size_t)N_NODES * H1 * 4);
    float*  a_s2   = (float*)alloc((size_t)N_NODES * 4);
    float*  a_d2   = (float*)alloc((size_t)N_NODES * 4);
    float*  pooled = (float*)alloc((size_t)N_GRAPHS * C2 * 4);
    float*  fold   = (float*)alloc((size_t)700 * 4);
    uint32* xbf    = (uint32*)alloc((size_t)N_NODES * 20 * 4);        // [N][40] bf16
    short*  aggx   = (short*)alloc((size_t)N_NODES * 400 * 2 + 256);  // [N*10][40] bf16 + slack
    uint32* x2p    = (uint32*)alloc((size_t)N_NODES * 176 * 4);       // [N][352] bf16
    unsigned short* h2b = (unsigned short*)alloc((size_t)N_NODES * C2 * 2);
    uint32* W1g    = (uint32*)alloc((size_t)10 * 2 * 3 * 64 * 16);
    uint32* W2f    = (uint32*)alloc((size_t)11 * 8 * 64 * 16);
    float*  out2   = (float*)aggx;  // aggx dead after k_gemm1b; 25.6 MB fits in 40 MB

    hipMemsetAsync(deg, 0, (size_t)N_NODES * 4, stream);
    hipMemsetAsync(pooled, 0, (size_t)N_GRAPHS * C2 * 4, stream);

    k_count<<<(N_EDGES + 255) / 256, 256, 0, stream>>>(dst, deg);
    k_bsum<<<NB256, 256, 0, stream>>>(deg, bsum);
    k_bscan<<<1, 256, 0, stream>>>(bsum, bpre);
    k_boffs<<<NB256, 256, 0, stream>>>(deg, bpre, offs, cursor);
    k_fill<<<(N_EDGES + 255) / 256, 256, 0, stream>>>(src, dst, cursor, csr);

    k_prep<<<XB + 3 + 15 + 22, 256, 0, stream>>>(x, W1, att_src1, att_dst1, b1, W2,
                                                 xbf, fold, W1g, W2f);
    k_att1<<<(N_NODES * 20 + 255) / 256, 256, 0, stream>>>(x, fold, a_s1, a_d1);

    k_aggx<<<N_NODES / 4, 256, 0, stream>>>((const uint4*)xbf, a_s1, a_d1, offs, csr,
                                            (uint4*)aggx);

    k_gemm1b<<<(N_NODES / 16 + 3) / 4, 256, 0, stream>>>(aggx, (const short8*)W1g,
                                                         (unsigned short*)x2p);

    k_gemm2<<<(N_NODES / 16 + 3) / 4, 256, 0, stream>>>((const short*)x2p, (const short8*)W2f,
                                                        att_src2, att_dst2, h2b, a_s2, a_d2);

    k_agg2<<<N_NODES / 4, 256, 0, stream>>>((const uint4*)h2b, a_s2, a_d2, offs, csr, b2, out2);

    k_pool<<<(N_NODES + 49) / 50, 128, 0, stream>>>(out2, batch, pooled);

    k_head<<<N_GRAPHS, 128, 0, stream>>>(pooled, Wg, bg, Wo, bo, (float*)d_out);
}